// Round 4
// baseline (81.272 us; speedup 1.0000x reference)
//
#include <hip/hip_runtime.h>

// Guitar string (Karplus-Strong waveguide), MI355X gfx950.
//
// LTI reformulation (validated r2-r6): both parities evolve by C = A*B
// (5 taps, lag QB=DU+DD+2). Round 11: evolve with D = C^16 (65 taps,
// lag E16=16QB) -- same FLOPs as two C^8 steps but HALF the barrier/
// latency epochs (15 -> 7+1), which is where ~54% of the time went
// (VALUBusy 46%, HBM 10%, issue floor ~18us vs 43.8us measured pass-1).
//   x_k = D^k (0.5 e);  S7 = sum_{k=0..7} x_k
//   E14 = S7 + C^8 (S7 - x7),   y15 = C^8 x7
//   then the validated epilogue on (E14, y15):
//   E61 = (1+C^2)(1+C^4) E14 + (1+C^2) y15,  z62 = C^4 y15,
//   U = (1+C) E61 + z62,  ls = (1+B)U + C z62,  rs = (1+A)U + C z62.
// Pass-0: 4 D-steps; sg = x0+..+x3, zg = x4. Pass-1: stage x4, 3 D-steps
// (acc = x4+x5+x6; G = sg+acc = S7-x7), combine, epilogue.
// acc-adds use the VALIDITY mask s*E16 (required for G's window reach
// down to 3*E16-8); conv/write keep (s+1)*E16 (chunk0: HALO, zeros flow).
//
// Taps: built per-block in LDS, lane-parallel, barrier-staged levels
// (q2 -> q4 -> q8 -> q16 as 1D convs; ~0.2us, tiny liveness -- avoids
// both r9's Cf spill disaster and r10's ~5us gs_taps serialization).
//
// Geometry: 64 rows x 4 chunks of 8000. SPAN=16384, HALO=8384 >= 4*E16
// (E16=16QB<=2096; QB<=131). PADF=1056 >= E8+8 (combine window). Pass-1
// combine/epilogue reach: F0=7*E8; worst epilogue reach 8382 <= HALO.

#define TLEN   32000
#define NROW   64
#define CHUNK  8000
#define NTH    1024
#define PT     16
#define PT4    (PT/4)
#define SPAN   (NTH*PT)        // 16384
#define HALO   (SPAN-CHUNK)    // 8384
#define PADF   1056            // front zero pad >= E8 (1048)
#define BUF    (PADF+SPAN)     // 17440 floats = 69.76 KB per buffer

__device__ inline int swz4(int f) {        // f: float index, multiple of 4
  int B = f >> 2;
  B ^= (B >> 3) & 7;                       // permute 16B blocks in 8-groups
  return B << 2;
}

__device__ inline float sgprf(float x) {
  return __uint_as_float(__builtin_amdgcn_readfirstlane(__float_as_uint(x)));
}
__device__ inline int sgpri(int x) {
  return __builtin_amdgcn_readfirstlane(x);
}

template<int NF4>
__device__ inline void ldwin(const float* b, int basef, float* v) {
#pragma unroll
  for (int i = 0; i < NF4; ++i) {
    float4 t4 = *(const float4*)&b[swz4(basef + 4*i)];
    v[4*i+0] = t4.x; v[4*i+1] = t4.y; v[4*i+2] = t4.z; v[4*i+3] = t4.w;
  }
}

__device__ inline void stown(float* b, const int* wro, const float* v) {
#pragma unroll
  for (int k = 0; k < PT4; ++k)
    *(float4*)&b[wro[k]] = make_float4(v[4*k], v[4*k+1], v[4*k+2], v[4*k+3]);
}

__global__ __launch_bounds__(NTH, 4)
void gs_pass(const int* __restrict__ lenp, const float* __restrict__ pp,
             const float* __restrict__ exc,
             float* __restrict__ zg, float* __restrict__ sg,
             float* __restrict__ lout, float* __restrict__ rout, int pass)
{
  __shared__ __align__(16) float bufA[BUF];
  __shared__ __align__(16) float bufB[BUF];
  __shared__ float tq2e[25];   // q2 at [8..16], zero-padded
  __shared__ float tq4e[49];   // q4 at [16..32]
  __shared__ float tq8e[97];   // q8 at [32..64]
  __shared__ float tq16[65];   // q16 (D taps)
  __shared__ float teps[40];   // T2@0(12) TQ@16(8) TB@24(7) TA@32(5)
  __shared__ int   tapsI[8];   // E16 E8 L2e L4 LQe LBe LAe

  const int row   = blockIdx.x >> 2;
  const int chunk = blockIdx.x & 3;
  const int t0    = chunk * CHUNK;
  const int tid   = threadIdx.x;
  const int sbase = tid * PT;
  const size_t rb = (size_t)row * TLEN;
  const int steps = pass ? 3 : 4;

  const float4 f4z = make_float4(0.f, 0.f, 0.f, 0.f);

  // ---- hoisted staging loads (HBM latency hides under the tap build) ----
  float4 st[4];
#pragma unroll
  for (int k = 0; k < 4; ++k) {
    int s4 = tid*4 + k*(NTH*4);
    int t  = t0 - HALO + s4;
    st[k] = f4z;
    if (t >= 0) {
      if (pass == 0) {
        float4 e = *(const float4*)&exc[rb + t];
        st[k] = make_float4(0.5f*e.x, 0.5f*e.y, 0.5f*e.z, 0.5f*e.w);
      } else {
        st[k] = *(const float4*)&zg[rb + t];
      }
    }
  }

  // ---- in-LDS tap build: barrier-staged 1D convolutions ----
  if (tid < 25) tq2e[tid] = 0.f;
  if (tid < 49) tq4e[tid] = 0.f;
  if (tid < 97) tq8e[tid] = 0.f;
  if (tid < 40) teps[tid] = 0.f;
  __syncthreads();
  if (tid == 0) {
    const float Lf  = (float)lenp[0];
    const float p   = 0.1f + 0.8f * pp[0];
    const float nUp = Lf * p;
    const float nDn = Lf * (1.0f - p);
    const int DU = (int)ceilf(nUp);
    const int DD = (int)ceilf(nDn);
    const float fU = (float)DU - nUp;
    const float fD = (float)DD - nDn;
    const float GN  = -0.99f * 0.999f;
    const float GB2 = -0.99f * 0.999f * 0.5f;
    const float a0 = GN * (1.0f - fU);
    const float a1 = GN * fU;
    const float w0 = 1.0f - fD, w1 = fD;
    const float b0 = GB2 * (0.3f * w0);
    const float b1 = GB2 * (w0 + 0.3f * w1);
    const float b2 = GB2 * (0.7f * w0 + w1);
    const float b3 = GB2 * (0.7f * w1);
    const int QB = DU + DD + 2;
    float q[5] = {0.f, 0.f, 0.f, 0.f, 0.f};
    q[0] += a0*b0; q[1] += a0*b1; q[2] += a0*b2; q[3] += a0*b3;
    q[1] += a1*b0; q[2] += a1*b1; q[3] += a1*b2; q[4] += a1*b3;
    float q2a[9];
#pragma unroll
    for (int m = 0; m < 9; ++m) q2a[m] = 0.f;
#pragma unroll
    for (int i = 0; i < 5; ++i)
#pragma unroll
      for (int j = 0; j < 5; ++j) q2a[i+j] = fmaf(q[i], q[j], q2a[i+j]);
#pragma unroll
    for (int i = 0; i < 9; ++i) tq2e[8 + i] = q2a[i];
    const int L2 = 2*QB, L4 = 4*QB, LQ = QB, LB = DD + 2, LA = DU;
    const int L2e = (L2+3)&~3, LQe = (LQ+3)&~3,
              LBe = (LB+3)&~3, LAe = (LA+3)&~3;
#pragma unroll
    for (int i = 0; i < 9; ++i) teps[(L2e - L2) + i] = q2a[i];
#pragma unroll
    for (int i = 0; i < 5; ++i) teps[16 + (LQe - LQ) + i] = q[i];
    teps[24 + (LBe-LB) + 0] = b0; teps[24 + (LBe-LB) + 1] = b1;
    teps[24 + (LBe-LB) + 2] = b2; teps[24 + (LBe-LB) + 3] = b3;
    teps[32 + (LAe-LA) + 0] = a0; teps[32 + (LAe-LA) + 1] = a1;
    tapsI[0] = 16*QB; tapsI[1] = 8*QB; tapsI[2] = L2e; tapsI[3] = L4;
    tapsI[4] = LQe;   tapsI[5] = LBe;  tapsI[6] = LAe;
  }
  __syncthreads();
  if (tid < 17) {                          // q4 = q2 (*) q2
    float s = 0.f;
#pragma unroll
    for (int i = 0; i < 9; ++i) s = fmaf(tq2e[8+i], tq2e[8 + tid - i], s);
    tq4e[16 + tid] = s;
  }
  __syncthreads();
  if (tid < 33) {                          // q8 = q4 (*) q4
    float s = 0.f;
#pragma unroll
    for (int i = 0; i < 17; ++i) s = fmaf(tq4e[16+i], tq4e[16 + tid - i], s);
    tq8e[32 + tid] = s;
  }
  __syncthreads();
  if (tid < 65) {                          // q16 = q8 (*) q8
    float s = 0.f;
#pragma unroll
    for (int i = 0; i < 33; ++i) s = fmaf(tq8e[32+i], tq8e[32 + tid - i], s);
    tq16[tid] = s;
  }

  // ---- staging writes ----
  if (tid * 4 < PADF) {
    *(float4*)&bufA[swz4(tid*4)] = f4z;
    *(float4*)&bufB[swz4(tid*4)] = f4z;
  }
  if (chunk == 0) {                        // true zeros at t<0
    for (int s4 = tid*4; s4 < HALO; s4 += NTH*4)
      *(float4*)&bufB[swz4(PADF + s4)] = f4z;
  }
#pragma unroll
  for (int k = 0; k < 4; ++k)
    *(float4*)&bufA[swz4(PADF + tid*4 + k*(NTH*4))] = st[k];
  __syncthreads();

  // ---- taps -> SGPR ----
  float W16[65];
#pragma unroll
  for (int m = 0; m < 65; ++m) W16[m] = sgprf(tq16[m]);
  const int E16 = sgpri(tapsI[0]);         // 16*QB <= 2096, mult of 16

  int rdoD[20], wro[PT4];
#pragma unroll
  for (int i = 0; i < 20; ++i) rdoD[i] = swz4(PADF + sbase - E16 + 4*i);
#pragma unroll
  for (int k = 0; k < PT4; ++k) wro[k] = swz4(PADF + sbase + 4*k);

  float* cur = bufA;
  float* nxt = bufB;

  float z[PT], acc[PT];
#pragma unroll
  for (int k = 0; k < PT4; ++k) {
    float4 t4 = *(const float4*)&cur[wro[k]];
    z[4*k+0] = t4.x; z[4*k+1] = t4.y; z[4*k+2] = t4.z; z[4*k+3] = t4.w;
  }
#pragma unroll
  for (int j = 0; j < PT; ++j) acc[j] = 0.f;

  // ---- evolve: x -> D x, acc += pre-update x ----
  for (int s = 0; s < steps; ++s) {
    const int wlim = (chunk == 0) ? HALO : (s + 1) * E16;
    const int alim = (chunk == 0) ? HALO : (pass ? s * E16 : wlim);
    if (sbase + PT > alim) {
#pragma unroll
      for (int j = 0; j < PT; ++j) acc[j] += z[j];
    }
    if (sbase + PT > wlim) {
      float nz[PT];
#pragma unroll
      for (int j = 0; j < PT; ++j) nz[j] = 0.f;
#pragma unroll
      for (int c = 0; c < 5; ++c) {        // stream window in 16f chunks
        float vv[16];
#pragma unroll
        for (int i = 0; i < 4; ++i) {
          float4 t4 = *(const float4*)&cur[rdoD[4*c + i]];
          vv[4*i+0] = t4.x; vv[4*i+1] = t4.y;
          vv[4*i+2] = t4.z; vv[4*i+3] = t4.w;
        }
#pragma unroll
        for (int mi = 0; mi < 16; ++mi) {
          const int idx = 16*c + mi;
#pragma unroll
          for (int j = 0; j < PT; ++j) {
            const int m = idx - j;         // compile-time pruned
            if (m >= 0 && m < 65) nz[j] = fmaf(W16[m], vv[mi], nz[j]);
          }
        }
      }
#pragma unroll
      for (int j = 0; j < PT; ++j) z[j] = nz[j];
      stown(nxt, wro, z);
    }
    __syncthreads();
    float* tp = cur; cur = nxt; nxt = tp;
  }

  if (pass == 0) {
    // cur = x4; stage acc = x0+..+x3; write back own region.
    stown(nxt, wro, acc);
    __syncthreads();
#pragma unroll
    for (int k = 0; k < 2; ++k) {
      int s4 = HALO + tid*4 + k*(NTH*4);
      if (s4 < SPAN) {
        int t = t0 + s4 - HALO;
        *(float4*)&zg[rb + t] = *(const float4*)&cur[swz4(PADF + s4)];
        *(float4*)&sg[rb + t] = *(const float4*)&nxt[swz4(PADF + s4)];
      }
    }
    return;
  }

  // ============== pass 1: combine then epilogue =========================
  // cur = bufB = x7, nxt = bufA; z = x7 own; acc = x4+x5+x6.
  stown(nxt, wro, acc);
  __syncthreads();
  {
    const int SG_LO = 3 * E16 - 64;        // G needed down to 3*E16-8
#pragma unroll
    for (int k = 0; k < 4; ++k) {
      int s4 = tid*4 + k*(NTH*4);
      int t  = t0 - HALO + s4;
      float4 sv = f4z;
      if (t >= 0 && (chunk == 0 || s4 >= SG_LO))
        sv = *(const float4*)&sg[rb + t];
      int o = swz4(PADF + s4);
      float4 a4 = *(const float4*)&nxt[o];
      *(float4*)&nxt[o] = make_float4(a4.x + sv.x, a4.y + sv.y,
                                      a4.z + sv.z, a4.w + sv.w);
    }
  }
  __syncthreads();
  // nxt = G = S7 - x7.  Combine: E14 = G + x7 + C^8 G ; y15 = C^8 x7.
  asm volatile("" ::: "memory");           // keep W8 load out of evolve
  float W8[33];
#pragma unroll
  for (int m = 0; m < 33; ++m) W8[m] = sgprf(tq8e[32 + m]);
  const int E8 = sgpri(tapsI[1]);
  const int F0 = 7 * E8;
  const bool ae = (chunk == 0) || (sbase + PT > F0);
  float E14[PT], Y15[PT];
  if (ae) {
    int rdo8[12];
#pragma unroll
    for (int i = 0; i < 12; ++i) rdo8[i] = swz4(PADF + sbase - E8 + 4*i);
    float g0[PT];
#pragma unroll
    for (int k = 0; k < PT4; ++k) {
      float4 t4 = *(const float4*)&nxt[wro[k]];
      g0[4*k+0] = t4.x; g0[4*k+1] = t4.y; g0[4*k+2] = t4.z; g0[4*k+3] = t4.w;
    }
    float v[48];
#pragma unroll
    for (int i = 0; i < 12; ++i) {
      float4 t4 = *(const float4*)&nxt[rdo8[i]];
      v[4*i+0] = t4.x; v[4*i+1] = t4.y; v[4*i+2] = t4.z; v[4*i+3] = t4.w;
    }
#pragma unroll
    for (int j = 0; j < PT; ++j) {
      float sv = g0[j] + z[j];
#pragma unroll
      for (int m = 0; m < 33; ++m) sv = fmaf(W8[m], v[j+m], sv);
      E14[j] = sv;
    }
#pragma unroll
    for (int i = 0; i < 12; ++i) {
      float4 t4 = *(const float4*)&cur[rdo8[i]];
      v[4*i+0] = t4.x; v[4*i+1] = t4.y; v[4*i+2] = t4.z; v[4*i+3] = t4.w;
    }
#pragma unroll
    for (int j = 0; j < PT; ++j) {
      float sv = W8[0] * v[j];
#pragma unroll
      for (int m = 1; m < 33; ++m) sv = fmaf(W8[m], v[j+m], sv);
      Y15[j] = sv;
    }
  }
  __syncthreads();
  if (ae) {
    stown(nxt, wro, E14);                  // nxt := E14 buffer
    stown(cur, wro, Y15);                  // cur := y15 buffer
#pragma unroll
    for (int j = 0; j < PT; ++j) z[j] = Y15[j];
  }
  __syncthreads();

  // ---- epilogue taps (LDS -> SGPR) ----
  asm volatile("" ::: "memory");
  float q4f[17], T2[12], TQ[8], TB[7], TA[5];
#pragma unroll
  for (int i = 0; i < 17; ++i) q4f[i] = sgprf(tq4e[16 + i]);
#pragma unroll
  for (int m = 0; m < 12; ++m) T2[m] = sgprf(teps[m]);
#pragma unroll
  for (int m = 0; m < 8; ++m) TQ[m] = sgprf(teps[16 + m]);
#pragma unroll
  for (int m = 0; m < 7; ++m) TB[m] = sgprf(teps[24 + m]);
#pragma unroll
  for (int m = 0; m < 5; ++m) TA[m] = sgprf(teps[32 + m]);
  const int L2e = sgpri(tapsI[2]), L4  = sgpri(tapsI[3]),
            LQe = sgpri(tapsI[4]), LBe = sgpri(tapsI[5]),
            LAe = sgpri(tapsI[6]);

  // Ph-A: H1 = (1+C^2)E14 ; Y2 = (1+C^2)y15 ; z62 = C^4 y15
  float H1[PT], Y2[PT], z62[PT];
  if (ae) {
    float e0[PT];
#pragma unroll
    for (int k = 0; k < PT4; ++k) {
      float4 t4 = *(const float4*)&nxt[wro[k]];
      e0[4*k+0] = t4.x; e0[4*k+1] = t4.y; e0[4*k+2] = t4.z; e0[4*k+3] = t4.w;
    }
    float w[28];
    ldwin<7>(nxt, PADF + sbase - L2e, w);
#pragma unroll
    for (int j = 0; j < PT; ++j) {
      float sv = e0[j];
#pragma unroll
      for (int m = 0; m < 12; ++m) sv = fmaf(T2[m], w[j+m], sv);
      H1[j] = sv;
    }
    ldwin<7>(cur, PADF + sbase - L2e, w);
#pragma unroll
    for (int j = 0; j < PT; ++j) {
      float sv = z[j];
#pragma unroll
      for (int m = 0; m < 12; ++m) sv = fmaf(T2[m], w[j+m], sv);
      Y2[j] = sv;
    }
    float w4[32];
    ldwin<8>(cur, PADF + sbase - L4, w4);    // L4 = 4QB, multiple of 4
#pragma unroll
    for (int j = 0; j < PT; ++j) {
      float sv = q4f[0] * w4[j];
#pragma unroll
      for (int m = 1; m < 17; ++m) sv = fmaf(q4f[m], w4[j+m], sv);
      z62[j] = sv;
    }
  }
  __syncthreads();
  if (ae) { stown(nxt, wro, H1); stown(cur, wro, z62); }
  __syncthreads();

  // Ph-B: E61 = H1 + C^4 H1 + Y2
  float E61[PT];
  if (ae) {
    float w4[32];
    ldwin<8>(nxt, PADF + sbase - L4, w4);
#pragma unroll
    for (int j = 0; j < PT; ++j) {
      float sv = H1[j] + Y2[j];
#pragma unroll
      for (int m = 0; m < 17; ++m) sv = fmaf(q4f[m], w4[j+m], sv);
      E61[j] = sv;
    }
  }
  __syncthreads();
  if (ae) stown(nxt, wro, E61);
  __syncthreads();

  // Ph-C: U = E61 + C E61 + z62 ; V = C z62
  float U[PT], V[PT];
  if (ae) {
    float w[24];
    ldwin<6>(nxt, PADF + sbase - LQe, w);
#pragma unroll
    for (int j = 0; j < PT; ++j) {
      float sv = E61[j] + z62[j];
#pragma unroll
      for (int m = 0; m < 8; ++m) sv = fmaf(TQ[m], w[j+m], sv);
      U[j] = sv;
    }
    ldwin<6>(cur, PADF + sbase - LQe, w);
#pragma unroll
    for (int j = 0; j < PT; ++j) {
      float sv = TQ[0] * w[j];
#pragma unroll
      for (int m = 1; m < 8; ++m) sv = fmaf(TQ[m], w[j+m], sv);
      V[j] = sv;
    }
  }
  __syncthreads();
  if (ae) stown(nxt, wro, U);
  __syncthreads();

  // Ph-D: s0 = U+V (into V); ls = s0 + B U; rs = s0 + A U
  float LSv[PT], RSv[PT];
  if (ae) {
#pragma unroll
    for (int j = 0; j < PT; ++j) V[j] += U[j];
    {
      float wb[24];
      ldwin<6>(nxt, PADF + sbase - LBe, wb);
#pragma unroll
      for (int j = 0; j < PT; ++j) {
        float sv = V[j];
#pragma unroll
        for (int m = 0; m < 7; ++m) sv = fmaf(TB[m], wb[j+m], sv);
        LSv[j] = sv;
      }
    }
    {
      float wa[20];
      ldwin<5>(nxt, PADF + sbase - LAe, wa);
#pragma unroll
      for (int j = 0; j < PT; ++j) {
        float sv = V[j];
#pragma unroll
        for (int m = 0; m < 5; ++m) sv = fmaf(TA[m], wa[j+m], sv);
        RSv[j] = sv;
      }
    }
  }
  __syncthreads();
  if (ae) { stown(cur, wro, LSv); stown(nxt, wro, RSv); }
  __syncthreads();

  // coalesced output store
#pragma unroll
  for (int k = 0; k < 2; ++k) {
    int s4 = HALO + tid*4 + k*(NTH*4);
    if (s4 < SPAN) {
      int t = t0 + s4 - HALO;
      *(float4*)&lout[rb + t] = *(const float4*)&cur[swz4(PADF + s4)];
      *(float4*)&rout[rb + t] = *(const float4*)&nxt[swz4(PADF + s4)];
    }
  }
}

extern "C" void kernel_launch(void* const* d_in, const int* in_sizes, int n_in,
                              void* d_out, int out_size, void* d_ws, size_t ws_size,
                              hipStream_t stream) {
  (void)in_sizes; (void)n_in; (void)out_size; (void)ws_size;

  const int*   lenp = (const int*)d_in[0];
  const float* pp   = (const float*)d_in[1];
  const float* exc  = (const float*)d_in[2];

  float* lout = (float*)d_out;                  // ls: 64*32000 f32
  float* rout = lout + (size_t)NROW * TLEN;     // rs

  float* zg = (float*)d_ws;                     // state x4 = C^64 e/2
  float* sg = zg + (size_t)NROW * TLEN;         // partial sum x0+..+x3

  dim3 grid(NROW * 4);
  gs_pass<<<grid, dim3(NTH), 0, stream>>>(lenp, pp, exc, zg, sg,
                                          lout, rout, 0);
  gs_pass<<<grid, dim3(NTH), 0, stream>>>(lenp, pp, exc, zg, sg,
                                          lout, rout, 1);
}